// Round 2
// baseline (447.613 us; speedup 1.0000x reference)
//
#include <hip/hip_runtime.h>
#include <cstdio>

// MinGRU: B=4, T=4096, D=1024, Di=2048
#define T_LEN 4096
#define B_SZ  4
#define D_IN  1024
#define DI    2048
#define MM    16384   // B*T
#define NC    32      // scan chunks
#define CHL   128     // chunk length (== GEMM M-tile)

typedef __attribute__((ext_vector_type(8))) __bf16 bf16x8;
typedef __attribute__((ext_vector_type(4))) float  f32x4;
typedef __attribute__((ext_vector_type(8))) unsigned short u16x8;

__device__ __forceinline__ unsigned short f2bf(float f){
  unsigned u = __builtin_bit_cast(unsigned, f);
  u += 0x7fffu + ((u >> 16) & 1u);   // round-to-nearest-even (inputs never NaN)
  return (unsigned short)(u >> 16);
}
__device__ __forceinline__ float bf2f_lo(unsigned u){  // low 16 bits
  return __builtin_bit_cast(float, u << 16);
}
__device__ __forceinline__ float bf2f_hi(unsigned u){  // high 16 bits
  return __builtin_bit_cast(float, u & 0xffff0000u);
}

__device__ __forceinline__ void async16(void* lds, const void* g){
  __builtin_amdgcn_global_load_lds((const __attribute__((address_space(1))) void*)g,
                                   (__attribute__((address_space(3))) void*)lds, 16, 0, 0);
}

// ---- fp32 -> bf16 convert of x (16.7M elems, 8 per thread) ----
__global__ __launch_bounds__(256) void k_convert_x(const float* __restrict__ x,
                                                   unsigned short* __restrict__ xb){
  size_t t = (size_t)blockIdx.x*256 + threadIdx.x;
  const float4* xi = (const float4*)x;
  float4 a = xi[2*t], b = xi[2*t+1];
  u16x8 o;
  o[0]=f2bf(a.x); o[1]=f2bf(a.y); o[2]=f2bf(a.z); o[3]=f2bf(a.w);
  o[4]=f2bf(b.x); o[5]=f2bf(b.y); o[6]=f2bf(b.z); o[7]=f2bf(b.w);
  ((u16x8*)xb)[t] = o;
}

// ---- transpose (SK,SN) fp32 -> (SN,SK) bf16; PERM=1 applies hidden/gate
// 16-column interleave: dst row n <- src col 16*(n>>5) + (n&15) + (n&16 ? 2048 : 0) ----
template<int PERM>
__global__ __launch_bounds__(256) void k_transpose(const float* __restrict__ src,
                                                   unsigned short* __restrict__ dst,
                                                   int SK, int SN){
  __shared__ float tile[64][65];
  int n0 = blockIdx.x*64, k0 = blockIdx.y*64;
  #pragma unroll
  for(int it=0; it<16; it++){
    int idx = it*256 + threadIdx.x;
    int kk = idx>>6, nn = idx&63;
    int n = n0+nn;
    int col = PERM ? (((n>>5)<<4) + (n&15) + ((n&16)?2048:0)) : n;
    tile[kk][nn] = src[(size_t)(k0+kk)*SN + col];
  }
  __syncthreads();
  #pragma unroll
  for(int it=0; it<16; it++){
    int idx = it*256 + threadIdx.x;
    int nn = idx>>6, kk = idx&63;
    dst[(size_t)(n0+nn)*SK + k0+kk] = f2bf(tile[kk][nn]);
  }
}

// ---- bf16 MFMA GEMM, A(M,K) row-major, Bt(N,K) row-major, 128x128x32 tiles.
// EPI=0: store fp32 C0.  EPI=1: hidden/gate interleaved columns ->
// c = sigmoid(-gate) -> U0 (bf16), v = sigmoid(gate)*g(hidden) -> U1 (bf16).
template<int EPI>
__global__ __launch_bounds__(256, 2)
void k_gemm(const unsigned short* __restrict__ A, const unsigned short* __restrict__ Bt,
            float* __restrict__ C0, unsigned short* __restrict__ U0,
            unsigned short* __restrict__ U1, int M, int N, int K){
  __shared__ unsigned short lsA[128*32];
  __shared__ unsigned short lsB[128*32];
  int tid  = threadIdx.x;
  int lane = tid & 63, wave = tid >> 6;
  int wm = wave >> 1, wn = wave & 1;
  int cl = lane & 15, quad = lane >> 4;
  int m0 = blockIdx.y * 128, n0 = blockIdx.x * 128;

  f32x4 acc[4][4];
  #pragma unroll
  for(int i=0;i<4;i++)
    #pragma unroll
    for(int j=0;j<4;j++) acc[i][j] = (f32x4){0.f,0.f,0.f,0.f};

  // staging: thread tid -> row tid>>2 (and +64), 8-bf16 quarter tid&3;
  // LDS dest = wave-uniform base + lane*16 bytes (global_load_lds constraint)
  const unsigned short* gA = A  + (size_t)(m0 + (tid>>2))*K + (tid&3)*8;
  const unsigned short* gB = Bt + (size_t)(n0 + (tid>>2))*K + (tid&3)*8;
  unsigned short* dA = lsA + tid*8;
  unsigned short* dB = lsB + tid*8;

  for(int k0=0; k0<K; k0+=32){
    async16(dA,        gA + k0);
    async16(dA + 2048, gA + (size_t)64*K + k0);
    async16(dB,        gB + k0);
    async16(dB + 2048, gB + (size_t)64*K + k0);
    __syncthreads();
    bf16x8 fa[4], fb[4];
    #pragma unroll
    for(int t2=0;t2<4;t2++){
      fa[t2] = *(const bf16x8*)&lsA[(wm*64 + t2*16 + cl)*32 + quad*8];
      fb[t2] = *(const bf16x8*)&lsB[(wn*64 + t2*16 + cl)*32 + quad*8];
    }
    #pragma unroll
    for(int i=0;i<4;i++)
      #pragma unroll
      for(int j=0;j<4;j++)
        acc[i][j] = __builtin_amdgcn_mfma_f32_16x16x32_bf16(fa[i], fb[j], acc[i][j], 0, 0, 0);
    __syncthreads();
  }

  if(EPI==0){
    #pragma unroll
    for(int i=0;i<4;i++)
      #pragma unroll
      for(int j=0;j<4;j++){
        int n = n0 + wn*64 + j*16 + cl;
        #pragma unroll
        for(int r=0;r<4;r++){
          int m = m0 + wm*64 + i*16 + quad*4 + r;
          C0[(size_t)m*N + n] = acc[i][j][r];
        }
      }
  } else {
    // col tiles: tj even = hidden, odd = gate, same 16 channels, same lane layout
    int ibase = ((n0 + wn*64) >> 1) + cl;
    #pragma unroll
    for(int i=0;i<4;i++)
      #pragma unroll
      for(int p=0;p<2;p++){
        f32x4 hh = acc[i][2*p], gg = acc[i][2*p+1];
        int ii = ibase + p*16;
        #pragma unroll
        for(int r=0;r<4;r++){
          int m = m0 + wm*64 + i*16 + quad*4 + r;   // flat (b*T+t)
          float gate = gg[r], hid = hh[r];
          float e  = __expf(gate);
          float cc = 1.f/(1.f + e);                 // sigmoid(-gate)
          float z  = (gate > 80.f) ? 1.f : e*cc;    // sigmoid(gate)
          float gv = (hid >= 0.f) ? (hid + 0.5f) : (1.f/(1.f + __expf(-hid)));
          U0[(size_t)m*DI + ii] = f2bf(cc);
          U1[(size_t)m*DI + ii] = f2bf(z*gv);
        }
      }
  }
}

// ---- scan phase A: per (b, chunk, 2-channel pair) affine summary ----
__global__ __launch_bounds__(256) void k_scanA(const unsigned* __restrict__ cp,
                                               const unsigned* __restrict__ vp,
                                               float* __restrict__ Ap,
                                               float* __restrict__ Vp){
  int t = blockIdx.x*256 + threadIdx.x;     // 131072 = B*NC*DI/2
  int i2 = t & (DI/2 - 1);
  int ch = (t >> 10) & (NC-1);
  int b  = t >> 15;
  size_t base = ((size_t)(b*T_LEN + ch*CHL))*(DI/2) + i2;
  float A0=1.f, V0=0.f, A1=1.f, V1=0.f;
  #pragma unroll 8
  for(int s=0; s<CHL; s++){
    unsigned cu = cp[base], vu = vp[base];
    float c0=bf2f_lo(cu), c1=bf2f_hi(cu), v0=bf2f_lo(vu), v1=bf2f_hi(vu);
    A0 *= c0; V0 = fmaf(c0, V0, v0);
    A1 *= c1; V1 = fmaf(c1, V1, v1);
    base += DI/2;
  }
  size_t o = (size_t)(b*NC + ch)*DI + 2*i2;
  Ap[o] = A0; Ap[o+1] = A1;
  Vp[o] = V0; Vp[o+1] = V1;
}

// ---- scan phase B: sequential combine over 32 chunks per channel ----
__global__ __launch_bounds__(256) void k_scanB(const float* __restrict__ prev,
                                               const float* __restrict__ Ap,
                                               const float* __restrict__ Vp,
                                               float* __restrict__ hin){
  int t = blockIdx.x*256 + threadIdx.x;     // 8192 = B*DI
  int i = t & (DI-1); int b = t >> 11;
  float h = fmaxf(prev[t], 1e-8f);          // h_0
  for(int ch=0; ch<NC; ch++){
    size_t o = (size_t)(b*NC + ch)*DI + i;
    hin[o] = h;
    h = fmaf(Ap[o], h, Vp[o]);
  }
}

// ---- scan phase C: full recurrence per chunk; h (bf16) overwrites v in place;
//      next_hidden (fp32) from last chunk ----
__global__ __launch_bounds__(256) void k_scanC(const unsigned* __restrict__ cp,
                                               unsigned* __restrict__ vp,
                                               const float* __restrict__ hin,
                                               float* __restrict__ nh){
  int t = blockIdx.x*256 + threadIdx.x;     // 131072
  int i2 = t & (DI/2 - 1);
  int ch = (t >> 10) & (NC-1);
  int b  = t >> 15;
  size_t base = ((size_t)(b*T_LEN + ch*CHL))*(DI/2) + i2;
  size_t ho = (size_t)(b*NC + ch)*DI + 2*i2;
  float h0 = hin[ho], h1 = hin[ho+1];
  #pragma unroll 4
  for(int s=0; s<CHL; s++){
    unsigned cu = cp[base], vu = vp[base];
    h0 = fmaf(bf2f_lo(cu), h0, bf2f_lo(vu));
    h1 = fmaf(bf2f_hi(cu), h1, bf2f_hi(vu));
    vp[base] = (unsigned)f2bf(h0) | ((unsigned)f2bf(h1) << 16);
    base += DI/2;
  }
  if(ch == NC-1){ nh[b*DI + 2*i2] = h0; nh[b*DI + 2*i2 + 1] = h1; }
}

extern "C" void kernel_launch(void* const* d_in, const int* in_sizes, int n_in,
                              void* d_out, int out_size, void* d_ws, size_t ws_size,
                              hipStream_t stream){
  const float* x    = (const float*)d_in[0];   // (4,4096,1024)
  const float* prev = (const float*)d_in[1];   // (4,2048)
  const float* Whg  = (const float*)d_in[2];   // (1024,4096)
  const float* Wout = (const float*)d_in[3];   // (2048,1024)
  float* out = (float*)d_out;                  // (4,4096,1024) fp32
  float* nh  = out + (size_t)MM*D_IN;          // (4,2048) fp32

  // workspace layout (total 116,391,936 B)
  const size_t NEED = 116391936;
  if(ws_size < NEED){
    fprintf(stderr, "kernel_launch: ws_size=%zu < needed %zu — aborting launch\n",
            ws_size, NEED);
    return;
  }
  char* ws = (char*)d_ws;
  unsigned short* xb = (unsigned short*)(ws);                    // 33,554,432 B bf16 x
  unsigned short* wt = (unsigned short*)(ws + 33554432);         //  8,388,608 B (4096x1024)
  unsigned short* wo = (unsigned short*)(ws + 41943040);         //  4,194,304 B (1024x2048)
  unsigned short* v  = (unsigned short*)(ws + 46137344);         // 67,108,864 B bf16 v (h in-place)
  float* Ap  = (float*)(ws + 113246208);                         // 1,048,576 B
  float* Vp  = (float*)(ws + 114294784);                         // 1,048,576 B
  float* hin = (float*)(ws + 115343360);                         // 1,048,576 B
  // c (bf16, 33.5M elems = 64 MB) parked in d_out's `out` region (dead until GEMM2)
  unsigned short* c = (unsigned short*)d_out;

  k_convert_x<<<8192, 256, 0, stream>>>(x, xb);
  k_transpose<1><<<dim3(64,16), 256, 0, stream>>>(Whg,  wt, 1024, 4096);
  k_transpose<0><<<dim3(16,32), 256, 0, stream>>>(Wout, wo, 2048, 1024);

  // GEMM1: (16384x1024)x(1024x4096) -> c (d_out), v (ws)
  k_gemm<1><<<dim3(32,128), 256, 0, stream>>>(xb, wt, nullptr, c, v, MM, 2*DI, D_IN);

  k_scanA<<<512, 256, 0, stream>>>((const unsigned*)c, (const unsigned*)v, Ap, Vp);
  k_scanB<<<32,  256, 0, stream>>>(prev, Ap, Vp, hin);
  k_scanC<<<512, 256, 0, stream>>>((const unsigned*)c, (unsigned*)v, hin, nh);

  // GEMM2: (16384x2048)x(2048x1024) -> out  (overwrites the c region last)
  k_gemm<0><<<dim3(8,128), 256, 0, stream>>>(v, wo, out, nullptr, nullptr, MM, D_IN, DI);
}

// Round 3
// 424.690 us; speedup vs baseline: 1.0540x; 1.0540x over previous
//
#include <hip/hip_runtime.h>
#include <cstdio>

// MinGRU: B=4, T=4096, D=1024, Di=2048
#define T_LEN 4096
#define B_SZ  4
#define D_IN  1024
#define DI    2048
#define MM    16384   // B*T
#define NC    32      // scan chunks
#define CHL   128     // chunk length (== GEMM M-tile)

typedef __attribute__((ext_vector_type(8))) __bf16 bf16x8;
typedef __attribute__((ext_vector_type(4))) float  f32x4;
typedef __attribute__((ext_vector_type(8))) unsigned short u16x8;

__device__ __forceinline__ unsigned short f2bf(float f){
  unsigned u = __builtin_bit_cast(unsigned, f);
  u += 0x7fffu + ((u >> 16) & 1u);   // round-to-nearest-even (inputs never NaN)
  return (unsigned short)(u >> 16);
}
__device__ __forceinline__ float bf2f_lo(unsigned u){
  return __builtin_bit_cast(float, u << 16);
}
__device__ __forceinline__ float bf2f_hi(unsigned u){
  return __builtin_bit_cast(float, u & 0xffff0000u);
}

__device__ __forceinline__ void async16(void* lds, const void* g){
  __builtin_amdgcn_global_load_lds((const __attribute__((address_space(1))) void*)g,
                                   (__attribute__((address_space(3))) void*)lds, 16, 0, 0);
}

// ---- fp32 -> bf16 convert of x ----
__global__ __launch_bounds__(256) void k_convert_x(const float* __restrict__ x,
                                                   unsigned short* __restrict__ xb){
  size_t t = (size_t)blockIdx.x*256 + threadIdx.x;
  const float4* xi = (const float4*)x;
  float4 a = xi[2*t], b = xi[2*t+1];
  u16x8 o;
  o[0]=f2bf(a.x); o[1]=f2bf(a.y); o[2]=f2bf(a.z); o[3]=f2bf(a.w);
  o[4]=f2bf(b.x); o[5]=f2bf(b.y); o[6]=f2bf(b.z); o[7]=f2bf(b.w);
  ((u16x8*)xb)[t] = o;
}

// ---- transpose (SK,SN) fp32 -> (SN,SK) bf16; PERM=1 applies hidden/gate
// 16-column interleave: dst row n <- src col 16*(n>>5) + (n&15) + (n&16 ? 2048 : 0) ----
template<int PERM>
__global__ __launch_bounds__(256) void k_transpose(const float* __restrict__ src,
                                                   unsigned short* __restrict__ dst,
                                                   int SK, int SN){
  __shared__ float tile[64][65];
  int n0 = blockIdx.x*64, k0 = blockIdx.y*64;
  #pragma unroll
  for(int it=0; it<16; it++){
    int idx = it*256 + threadIdx.x;
    int kk = idx>>6, nn = idx&63;
    int n = n0+nn;
    int col = PERM ? (((n>>5)<<4) + (n&15) + ((n&16)?2048:0)) : n;
    tile[kk][nn] = src[(size_t)(k0+kk)*SN + col];
  }
  __syncthreads();
  #pragma unroll
  for(int it=0; it<16; it++){
    int idx = it*256 + threadIdx.x;
    int nn = idx>>6, kk = idx&63;
    dst[(size_t)(n0+nn)*SK + k0+kk] = f2bf(tile[kk][nn]);
  }
}

// ---- bf16 MFMA GEMM, A(M,K) row-major, Bt(N,K) row-major, 128x128x32 tiles.
// LDS k-chunk XOR swizzle: LDS slot c of row r holds global chunk c ^ ((r>>1)&3)
// -> quarter-wave ds_read_b128 covers all 32 banks (2-way, free) instead of 8-way.
// EPI=0: store fp32 C0.  EPI=1: hidden/gate interleaved columns ->
// c=sigmoid(-gate)->U0 (bf16), v=sigmoid(gate)*g(hidden)->U1 (bf16),
// plus fused chunk affine summary (scanA): Ap/Vp per (chunk, channel).
template<int EPI>
__global__ __launch_bounds__(256, 2)
void k_gemm(const unsigned short* __restrict__ A, const unsigned short* __restrict__ Bt,
            float* __restrict__ C0, unsigned short* __restrict__ U0,
            unsigned short* __restrict__ U1, float* __restrict__ Ap,
            float* __restrict__ Vp, int M, int N, int K){
  __shared__ unsigned short lsA[128*32];
  __shared__ unsigned short lsB[128*32];
  int tid  = threadIdx.x;
  int lane = tid & 63, wave = tid >> 6;
  int wm = wave >> 1, wn = wave & 1;
  int cl = lane & 15, quad = lane >> 4;
  int m0 = blockIdx.y * 128, n0 = blockIdx.x * 128;

  f32x4 acc[4][4];
  #pragma unroll
  for(int i=0;i<4;i++)
    #pragma unroll
    for(int j=0;j<4;j++) acc[i][j] = (f32x4){0.f,0.f,0.f,0.f};

  // staging: thread tid -> row tid>>2 (and +64), LDS slot tid&3 at base+lane*16;
  // global chunk fetched = slot ^ ((row>>1)&3)  (swizzle; row+64 gives same xor)
  int cs = (tid&3) ^ ((tid>>3)&3);
  const unsigned short* gA = A  + (size_t)(m0 + (tid>>2))*K + cs*8;
  const unsigned short* gB = Bt + (size_t)(n0 + (tid>>2))*K + cs*8;
  unsigned short* dA = lsA + tid*8;
  unsigned short* dB = lsB + tid*8;
  // reader: global chunk quad of row t2*16+cl lives at LDS slot quad ^ ((cl>>1)&3)
  int qa8 = (quad ^ ((cl>>1)&3)) * 8;

  for(int k0=0; k0<K; k0+=32){
    async16(dA,        gA + k0);
    async16(dA + 2048, gA + (size_t)64*K + k0);
    async16(dB,        gB + k0);
    async16(dB + 2048, gB + (size_t)64*K + k0);
    __syncthreads();
    bf16x8 fa[4], fb[4];
    #pragma unroll
    for(int t2=0;t2<4;t2++){
      fa[t2] = *(const bf16x8*)&lsA[(wm*64 + t2*16 + cl)*32 + qa8];
      fb[t2] = *(const bf16x8*)&lsB[(wn*64 + t2*16 + cl)*32 + qa8];
    }
    #pragma unroll
    for(int i=0;i<4;i++)
      #pragma unroll
      for(int j=0;j<4;j++)
        acc[i][j] = __builtin_amdgcn_mfma_f32_16x16x32_bf16(fa[i], fb[j], acc[i][j], 0, 0, 0);
    __syncthreads();
  }

  if(EPI==0){
    #pragma unroll
    for(int i=0;i<4;i++)
      #pragma unroll
      for(int j=0;j<4;j++){
        int n = n0 + wn*64 + j*16 + cl;
        #pragma unroll
        for(int r=0;r<4;r++){
          int m = m0 + wm*64 + i*16 + quad*4 + r;
          C0[(size_t)m*N + n] = acc[i][j][r];
        }
      }
  } else {
    // col tiles: tj even = hidden, odd = gate; 64 distinct channels per block.
    // Fused scanA: lane's 4 consecutive rows per (i,p) -> partial affine map,
    // seg-major in LDS (reused lsA/lsB), then 64 threads compose 32 segs each.
    float* lA_f = (float*)lsA;   // [seg(32)][ch(64)] = 8 KB
    float* lV_f = (float*)lsB;
    int ibase = ((n0 + wn*64) >> 1) + cl;
    #pragma unroll
    for(int i=0;i<4;i++)
      #pragma unroll
      for(int p=0;p<2;p++){
        f32x4 hh = acc[i][2*p], gg = acc[i][2*p+1];
        int ii = ibase + p*16;
        float pa = 1.f, pv = 0.f;
        #pragma unroll
        for(int r=0;r<4;r++){
          int m = m0 + wm*64 + i*16 + quad*4 + r;   // flat (b*T+t)
          float gate = gg[r], hid = hh[r];
          float e  = __expf(gate);
          float cc = 1.f/(1.f + e);                 // sigmoid(-gate)
          float z  = (gate > 80.f) ? 1.f : e*cc;    // sigmoid(gate)
          float gv = (hid >= 0.f) ? (hid + 0.5f) : (1.f/(1.f + __expf(-hid)));
          float vv = z*gv;
          U0[(size_t)m*DI + ii] = f2bf(cc);
          U1[(size_t)m*DI + ii] = f2bf(vv);
          pa *= cc;
          pv = fmaf(cc, pv, vv);
        }
        int seg = wm*16 + i*4 + quad;
        int chl = wn*32 + p*16 + cl;
        lA_f[seg*64 + chl] = pa;
        lV_f[seg*64 + chl] = pv;
      }
    __syncthreads();
    if(tid < 64){
      float Ac = 1.f, Vc = 0.f;
      #pragma unroll 8
      for(int s=0; s<32; s++){
        float a = lA_f[s*64 + tid], v = lV_f[s*64 + tid];
        Ac *= a;
        Vc = fmaf(a, Vc, v);
      }
      size_t o = (size_t)(m0 >> 7)*DI + (n0 >> 1) + tid;  // (b*NC+ch)*DI + channel
      Ap[o] = Ac; Vp[o] = Vc;
    }
  }
}

// ---- scan phase B: sequential combine over 32 chunks per channel ----
__global__ __launch_bounds__(256) void k_scanB(const float* __restrict__ prev,
                                               const float* __restrict__ Ap,
                                               const float* __restrict__ Vp,
                                               float* __restrict__ hin){
  int t = blockIdx.x*256 + threadIdx.x;     // 8192 = B*DI
  int i = t & (DI-1); int b = t >> 11;
  float h = fmaxf(prev[t], 1e-8f);          // h_0
  for(int ch=0; ch<NC; ch++){
    size_t o = (size_t)(b*NC + ch)*DI + i;
    hin[o] = h;
    h = fmaf(Ap[o], h, Vp[o]);
  }
}

// ---- scan phase C: full recurrence per chunk; h (bf16) overwrites v in place;
//      next_hidden (fp32) from last chunk ----
__global__ __launch_bounds__(256) void k_scanC(const unsigned* __restrict__ cp,
                                               unsigned* __restrict__ vp,
                                               const float* __restrict__ hin,
                                               float* __restrict__ nh){
  int t = blockIdx.x*256 + threadIdx.x;     // 131072
  int i2 = t & (DI/2 - 1);
  int ch = (t >> 10) & (NC-1);
  int b  = t >> 15;
  size_t base = ((size_t)(b*T_LEN + ch*CHL))*(DI/2) + i2;
  size_t ho = (size_t)(b*NC + ch)*DI + 2*i2;
  float h0 = hin[ho], h1 = hin[ho+1];
  #pragma unroll 4
  for(int s=0; s<CHL; s++){
    unsigned cu = cp[base], vu = vp[base];
    h0 = fmaf(bf2f_lo(cu), h0, bf2f_lo(vu));
    h1 = fmaf(bf2f_hi(cu), h1, bf2f_hi(vu));
    vp[base] = (unsigned)f2bf(h0) | ((unsigned)f2bf(h1) << 16);
    base += DI/2;
  }
  if(ch == NC-1){ nh[b*DI + 2*i2] = h0; nh[b*DI + 2*i2 + 1] = h1; }
}

extern "C" void kernel_launch(void* const* d_in, const int* in_sizes, int n_in,
                              void* d_out, int out_size, void* d_ws, size_t ws_size,
                              hipStream_t stream){
  const float* x    = (const float*)d_in[0];   // (4,4096,1024)
  const float* prev = (const float*)d_in[1];   // (4,2048)
  const float* Whg  = (const float*)d_in[2];   // (1024,4096)
  const float* Wout = (const float*)d_in[3];   // (2048,1024)
  float* out = (float*)d_out;                  // (4,4096,1024) fp32
  float* nh  = out + (size_t)MM*D_IN;          // (4,2048) fp32

  // workspace layout (total 116,391,936 B)
  const size_t NEED = 116391936;
  if(ws_size < NEED){
    fprintf(stderr, "kernel_launch: ws_size=%zu < needed %zu — aborting launch\n",
            ws_size, NEED);
    return;
  }
  char* ws = (char*)d_ws;
  unsigned short* xb = (unsigned short*)(ws);                    // 33,554,432 B bf16 x
  unsigned short* wt = (unsigned short*)(ws + 33554432);         //  8,388,608 B (4096x1024)
  unsigned short* wo = (unsigned short*)(ws + 41943040);         //  4,194,304 B (1024x2048)
  unsigned short* v  = (unsigned short*)(ws + 46137344);         // 67,108,864 B bf16 v (h in-place)
  float* Ap  = (float*)(ws + 113246208);                         // 1,048,576 B
  float* Vp  = (float*)(ws + 114294784);                         // 1,048,576 B
  float* hin = (float*)(ws + 115343360);                         // 1,048,576 B
  // c (bf16, 33.5M elems = 64 MB) parked in d_out's `out` region (dead until GEMM2)
  unsigned short* c = (unsigned short*)d_out;

  k_convert_x<<<8192, 256, 0, stream>>>(x, xb);
  k_transpose<1><<<dim3(64,16), 256, 0, stream>>>(Whg,  wt, 1024, 4096);
  k_transpose<0><<<dim3(16,32), 256, 0, stream>>>(Wout, wo, 2048, 1024);

  // GEMM1: (16384x1024)x(1024x4096) -> c (d_out), v (ws), fused scanA -> Ap/Vp
  k_gemm<1><<<dim3(32,128), 256, 0, stream>>>(xb, wt, nullptr, c, v, Ap, Vp,
                                              MM, 2*DI, D_IN);

  k_scanB<<<32,  256, 0, stream>>>(prev, Ap, Vp, hin);
  k_scanC<<<512, 256, 0, stream>>>((const unsigned*)c, (unsigned*)v, hin, nh);

  // GEMM2: (16384x2048)x(2048x1024) -> out  (overwrites the c region last)
  k_gemm<0><<<dim3(8,128), 256, 0, stream>>>(v, wo, out, nullptr, nullptr,
                                             nullptr, nullptr, MM, D_IN, DI);
}

// Round 4
// 424.622 us; speedup vs baseline: 1.0541x; 1.0002x over previous
//
#include <hip/hip_runtime.h>
#include <cstdio>

// MinGRU: B=4, T=4096, D=1024, Di=2048
#define T_LEN 4096
#define B_SZ  4
#define D_IN  1024
#define DI    2048
#define MM    16384   // B*T
#define NC2   64      // scan chunks (length 64)
#define CHL2  64      // scan chunk length

typedef __attribute__((ext_vector_type(8))) __bf16 bf16x8;
typedef __attribute__((ext_vector_type(4))) float  f32x4;
typedef __attribute__((ext_vector_type(8))) unsigned short u16x8;

__device__ __forceinline__ unsigned short f2bf(float f){
  unsigned u = __builtin_bit_cast(unsigned, f);
  u += 0x7fffu + ((u >> 16) & 1u);   // round-to-nearest-even (inputs never NaN)
  return (unsigned short)(u >> 16);
}
__device__ __forceinline__ float bf2f_lo(unsigned u){
  return __builtin_bit_cast(float, u << 16);
}
__device__ __forceinline__ float bf2f_hi(unsigned u){
  return __builtin_bit_cast(float, u & 0xffff0000u);
}

__device__ __forceinline__ void async16(void* lds, const void* g){
  __builtin_amdgcn_global_load_lds((const __attribute__((address_space(1))) void*)g,
                                   (__attribute__((address_space(3))) void*)lds, 16, 0, 0);
}

// ---- merged prep: fp32->bf16 convert of x + both weight transposes ----
// blocks [0,8192): convert x (8 elems/thread)
// blocks [8192,9216): Whg (1024,4096) -> wt (4096,1024) bf16, hidden/gate interleave
// blocks [9216,9728): Wout (2048,1024) -> wo (1024,2048) bf16
template<int PERM>
__device__ __forceinline__ void transpose_body(const float* __restrict__ src,
                                               unsigned short* __restrict__ dst,
                                               int n0, int k0, int SK, int SN,
                                               float (*tile)[65], int tid){
  #pragma unroll
  for(int it=0; it<16; it++){
    int idx = it*256 + tid;
    int kk = idx>>6, nn = idx&63;
    int n = n0+nn;
    int col = PERM ? (((n>>5)<<4) + (n&15) + ((n&16)?2048:0)) : n;
    tile[kk][nn] = src[(size_t)(k0+kk)*SN + col];
  }
  __syncthreads();
  #pragma unroll
  for(int it=0; it<16; it++){
    int idx = it*256 + tid;
    int nn = idx>>6, kk = idx&63;
    dst[(size_t)(n0+nn)*SK + k0+kk] = f2bf(tile[kk][nn]);
  }
}

__global__ __launch_bounds__(256) void k_prep(const float* __restrict__ x,
                                              unsigned short* __restrict__ xb,
                                              const float* __restrict__ Whg,
                                              unsigned short* __restrict__ wt,
                                              const float* __restrict__ Wout,
                                              unsigned short* __restrict__ wo){
  __shared__ float tile[64][65];
  int bid = blockIdx.x, tid = threadIdx.x;
  if(bid < 8192){
    size_t t = (size_t)bid*256 + tid;
    const float4* xi = (const float4*)x;
    float4 a = xi[2*t], b = xi[2*t+1];
    u16x8 o;
    o[0]=f2bf(a.x); o[1]=f2bf(a.y); o[2]=f2bf(a.z); o[3]=f2bf(a.w);
    o[4]=f2bf(b.x); o[5]=f2bf(b.y); o[6]=f2bf(b.z); o[7]=f2bf(b.w);
    ((u16x8*)xb)[t] = o;
  } else if(bid < 9216){
    int j = bid - 8192;
    transpose_body<1>(Whg, wt, (j&63)*64, (j>>6)*64, 1024, 4096, tile, tid);
  } else {
    int j = bid - 9216;
    transpose_body<0>(Wout, wo, (j&15)*64, (j>>4)*64, 2048, 1024, tile, tid);
  }
}

// ---- bf16 MFMA GEMM, A(M,K) row-major, Bt(N,K) row-major, 128x128x32 tiles.
// LDS k-chunk XOR swizzle: slot c of row r holds global chunk c ^ ((r>>1)&3).
// EPI=0: store fp32 C0.  EPI=1: hidden/gate interleaved columns ->
// c=sigmoid(-gate)->U0 (bf16), v=sigmoid(gate)*g(hidden)->U1 (bf16),
// plus fused HALF-chunk (64-row) affine summaries -> Ap/Vp.
template<int EPI>
__global__ __launch_bounds__(256, 2)
void k_gemm(const unsigned short* __restrict__ A, const unsigned short* __restrict__ Bt,
            float* __restrict__ C0, unsigned short* __restrict__ U0,
            unsigned short* __restrict__ U1, float* __restrict__ Ap,
            float* __restrict__ Vp, int M, int N, int K){
  __shared__ unsigned short lsA[128*32];
  __shared__ unsigned short lsB[128*32];
  int tid  = threadIdx.x;
  int lane = tid & 63, wave = tid >> 6;
  int wm = wave >> 1, wn = wave & 1;
  int cl = lane & 15, quad = lane >> 4;
  int m0 = blockIdx.y * 128, n0 = blockIdx.x * 128;

  f32x4 acc[4][4];
  #pragma unroll
  for(int i=0;i<4;i++)
    #pragma unroll
    for(int j=0;j<4;j++) acc[i][j] = (f32x4){0.f,0.f,0.f,0.f};

  int cs = (tid&3) ^ ((tid>>3)&3);
  const unsigned short* gA = A  + (size_t)(m0 + (tid>>2))*K + cs*8;
  const unsigned short* gB = Bt + (size_t)(n0 + (tid>>2))*K + cs*8;
  unsigned short* dA = lsA + tid*8;
  unsigned short* dB = lsB + tid*8;
  int qa8 = (quad ^ ((cl>>1)&3)) * 8;

  for(int k0=0; k0<K; k0+=32){
    async16(dA,        gA + k0);
    async16(dA + 2048, gA + (size_t)64*K + k0);
    async16(dB,        gB + k0);
    async16(dB + 2048, gB + (size_t)64*K + k0);
    __syncthreads();
    bf16x8 fa[4], fb[4];
    #pragma unroll
    for(int t2=0;t2<4;t2++){
      fa[t2] = *(const bf16x8*)&lsA[(wm*64 + t2*16 + cl)*32 + qa8];
      fb[t2] = *(const bf16x8*)&lsB[(wn*64 + t2*16 + cl)*32 + qa8];
    }
    #pragma unroll
    for(int i=0;i<4;i++)
      #pragma unroll
      for(int j=0;j<4;j++)
        acc[i][j] = __builtin_amdgcn_mfma_f32_16x16x32_bf16(fa[i], fb[j], acc[i][j], 0, 0, 0);
    __syncthreads();
  }

  if(EPI==0){
    #pragma unroll
    for(int i=0;i<4;i++)
      #pragma unroll
      for(int j=0;j<4;j++){
        int n = n0 + wn*64 + j*16 + cl;
        #pragma unroll
        for(int r=0;r<4;r++){
          int m = m0 + wm*64 + i*16 + quad*4 + r;
          C0[(size_t)m*N + n] = acc[i][j][r];
        }
      }
  } else {
    // Fused scan summary: per-lane 4-row partial maps -> seg-major LDS
    // (seg = 4-row group, 32 per block), then 128 threads compose 16 segs each
    // into two 64-row half-chunk summaries.
    float* lA_f = (float*)lsA;   // [seg(32)][ch(64)] = 8 KB
    float* lV_f = (float*)lsB;
    int ibase = ((n0 + wn*64) >> 1) + cl;
    #pragma unroll
    for(int i=0;i<4;i++)
      #pragma unroll
      for(int p=0;p<2;p++){
        f32x4 hh = acc[i][2*p], gg = acc[i][2*p+1];
        int ii = ibase + p*16;
        float pa = 1.f, pv = 0.f;
        #pragma unroll
        for(int r=0;r<4;r++){
          int m = m0 + wm*64 + i*16 + quad*4 + r;   // flat (b*T+t)
          float gate = gg[r], hid = hh[r];
          float e  = __expf(gate);
          float cc = 1.f/(1.f + e);                 // sigmoid(-gate)
          float z  = (gate > 80.f) ? 1.f : e*cc;    // sigmoid(gate)
          float gv = (hid >= 0.f) ? (hid + 0.5f) : (1.f/(1.f + __expf(-hid)));
          float vv = z*gv;
          U0[(size_t)m*DI + ii] = f2bf(cc);
          U1[(size_t)m*DI + ii] = f2bf(vv);
          pa *= cc;
          pv = fmaf(cc, pv, vv);
        }
        int seg = wm*16 + i*4 + quad;
        int chl = wn*32 + p*16 + cl;
        lA_f[seg*64 + chl] = pa;
        lV_f[seg*64 + chl] = pv;
      }
    __syncthreads();
    if(tid < 128){
      int ch = tid & 63, q = tid >> 6;
      float Ac = 1.f, Vc = 0.f;
      #pragma unroll 8
      for(int s=0; s<16; s++){
        int idx = (q*16 + s)*64 + ch;
        float a = lA_f[idx], v = lV_f[idx];
        Ac *= a;
        Vc = fmaf(a, Vc, v);
      }
      int b = m0 >> 12;
      int ch64 = ((m0 & 4095) >> 6) + q;            // 64-row chunk index in batch
      size_t o = (size_t)(b*NC2 + ch64)*DI + (n0 >> 1) + ch;
      Ap[o] = Ac; Vp[o] = Vc;
    }
  }
}

// ---- scan phase B: sequential combine over 64 chunks; hin written in-place
//      over Ap (read-then-write, same thread/index) ----
__global__ __launch_bounds__(256) void k_scanB(const float* __restrict__ prev,
                                               float* __restrict__ Ap,
                                               const float* __restrict__ Vp){
  int t = blockIdx.x*256 + threadIdx.x;     // 8192 = B*DI
  int i = t & (DI-1); int b = t >> 11;
  float h = fmaxf(prev[t], 1e-8f);          // h_0
  for(int ch=0; ch<NC2; ch++){
    size_t o = (size_t)(b*NC2 + ch)*DI + i;
    float a = Ap[o], vv = Vp[o];
    Ap[o] = h;                               // hin for this chunk
    h = fmaf(a, h, vv);
  }
}

// ---- scan phase C: recurrence per 64-chunk; h (bf16) overwrites v in place;
//      next_hidden (fp32) from last chunk ----
__global__ __launch_bounds__(256) void k_scanC(const unsigned* __restrict__ cp,
                                               unsigned* __restrict__ vp,
                                               const float* __restrict__ hin,
                                               float* __restrict__ nh){
  int t = blockIdx.x*256 + threadIdx.x;     // 262144 = B*NC2*DI/2
  int i2 = t & (DI/2 - 1);
  int ch = (t >> 10) & (NC2-1);
  int b  = t >> 16;
  size_t base = ((size_t)(b*T_LEN + ch*CHL2))*(DI/2) + i2;
  const float2* hin2 = (const float2*)hin;
  float2 h01 = hin2[(size_t)(b*NC2 + ch)*(DI/2) + i2];
  float h0 = h01.x, h1 = h01.y;
  #pragma unroll 4
  for(int s=0; s<CHL2; s++){
    unsigned cu = cp[base], vu = vp[base];
    h0 = fmaf(bf2f_lo(cu), h0, bf2f_lo(vu));
    h1 = fmaf(bf2f_hi(cu), h1, bf2f_hi(vu));
    vp[base] = (unsigned)f2bf(h0) | ((unsigned)f2bf(h1) << 16);
    base += DI/2;
  }
  if(ch == NC2-1){ nh[b*DI + 2*i2] = h0; nh[b*DI + 2*i2 + 1] = h1; }
}

extern "C" void kernel_launch(void* const* d_in, const int* in_sizes, int n_in,
                              void* d_out, int out_size, void* d_ws, size_t ws_size,
                              hipStream_t stream){
  const float* x    = (const float*)d_in[0];   // (4,4096,1024)
  const float* prev = (const float*)d_in[1];   // (4,2048)
  const float* Whg  = (const float*)d_in[2];   // (1024,4096)
  const float* Wout = (const float*)d_in[3];   // (2048,1024)
  float* out = (float*)d_out;                  // (4,4096,1024) fp32
  float* nh  = out + (size_t)MM*D_IN;          // (4,2048) fp32

  // workspace layout (total 117,440,512 B)
  const size_t NEED = 117440512;
  if(ws_size < NEED){
    fprintf(stderr, "kernel_launch: ws_size=%zu < needed %zu — aborting launch\n",
            ws_size, NEED);
    return;
  }
  char* ws = (char*)d_ws;
  unsigned short* xb = (unsigned short*)(ws);                    // 33,554,432 B bf16 x
  unsigned short* wt = (unsigned short*)(ws + 33554432);         //  8,388,608 B (4096x1024)
  unsigned short* wo = (unsigned short*)(ws + 41943040);         //  4,194,304 B (1024x2048)
  unsigned short* v  = (unsigned short*)(ws + 46137344);         // 67,108,864 B bf16 v (h in-place)
  float* Ap  = (float*)(ws + 113246208);                         // 2,097,152 B (hin in-place)
  float* Vp  = (float*)(ws + 115343360);                         // 2,097,152 B
  // c (bf16, 33.5M elems = 64 MB) parked in d_out's `out` region (dead until GEMM2)
  unsigned short* c = (unsigned short*)d_out;

  k_prep<<<9728, 256, 0, stream>>>(x, xb, Whg, wt, Wout, wo);

  // GEMM1: (16384x1024)x(1024x4096) -> c (d_out), v (ws), fused scanA -> Ap/Vp
  k_gemm<1><<<dim3(32,128), 256, 0, stream>>>(xb, wt, nullptr, c, v, Ap, Vp,
                                              MM, 2*DI, D_IN);

  k_scanB<<<32,   256, 0, stream>>>(prev, Ap, Vp);
  k_scanC<<<1024, 256, 0, stream>>>((const unsigned*)c, (unsigned*)v, Ap, nh);

  // GEMM2: (16384x2048)x(2048x1024) -> out  (overwrites the c region last)
  k_gemm<0><<<dim3(8,128), 256, 0, stream>>>(v, wo, out, nullptr, nullptr,
                                             nullptr, nullptr, MM, D_IN, DI);
}

// Round 5
// 421.698 us; speedup vs baseline: 1.0615x; 1.0069x over previous
//
#include <hip/hip_runtime.h>
#include <cstdio>

// MinGRU: B=4, T=4096, D=1024, Di=2048
#define T_LEN 4096
#define B_SZ  4
#define D_IN  1024
#define DI    2048
#define MM    16384   // B*T
#define NC2   128     // scan chunks (length 32)
#define CHL2  32      // scan chunk length

typedef __attribute__((ext_vector_type(8))) __bf16 bf16x8;
typedef __attribute__((ext_vector_type(4))) float  f32x4;
typedef __attribute__((ext_vector_type(8))) unsigned short u16x8;

__device__ __forceinline__ unsigned short f2bf(float f){
  unsigned u = __builtin_bit_cast(unsigned, f);
  u += 0x7fffu + ((u >> 16) & 1u);   // round-to-nearest-even (inputs never NaN)
  return (unsigned short)(u >> 16);
}
__device__ __forceinline__ float bf2f_lo(unsigned u){
  return __builtin_bit_cast(float, u << 16);
}
__device__ __forceinline__ float bf2f_hi(unsigned u){
  return __builtin_bit_cast(float, u & 0xffff0000u);
}
__device__ __forceinline__ float bf2f_s(unsigned short s){
  return __builtin_bit_cast(float, (unsigned)s << 16);
}

__device__ __forceinline__ void async16(void* lds, const void* g){
  __builtin_amdgcn_global_load_lds((const __attribute__((address_space(1))) void*)g,
                                   (__attribute__((address_space(3))) void*)lds, 16, 0, 0);
}

// ---- merged prep: fp32->bf16 convert of x + both weight transposes ----
template<int PERM>
__device__ __forceinline__ void transpose_body(const float* __restrict__ src,
                                               unsigned short* __restrict__ dst,
                                               int n0, int k0, int SK, int SN,
                                               float (*tile)[65], int tid){
  #pragma unroll
  for(int it=0; it<16; it++){
    int idx = it*256 + tid;
    int kk = idx>>6, nn = idx&63;
    int n = n0+nn;
    int col = PERM ? (((n>>5)<<4) + (n&15) + ((n&16)?2048:0)) : n;
    tile[kk][nn] = src[(size_t)(k0+kk)*SN + col];
  }
  __syncthreads();
  #pragma unroll
  for(int it=0; it<16; it++){
    int idx = it*256 + tid;
    int nn = idx>>6, kk = idx&63;
    dst[(size_t)(n0+nn)*SK + k0+kk] = f2bf(tile[kk][nn]);
  }
}

__global__ __launch_bounds__(256) void k_prep(const float* __restrict__ x,
                                              unsigned short* __restrict__ xb,
                                              const float* __restrict__ Whg,
                                              unsigned short* __restrict__ wt,
                                              const float* __restrict__ Wout,
                                              unsigned short* __restrict__ wo){
  __shared__ float tile[64][65];
  int bid = blockIdx.x, tid = threadIdx.x;
  if(bid < 8192){
    size_t t = (size_t)bid*256 + tid;
    const float4* xi = (const float4*)x;
    float4 a = xi[2*t], b = xi[2*t+1];
    u16x8 o;
    o[0]=f2bf(a.x); o[1]=f2bf(a.y); o[2]=f2bf(a.z); o[3]=f2bf(a.w);
    o[4]=f2bf(b.x); o[5]=f2bf(b.y); o[6]=f2bf(b.z); o[7]=f2bf(b.w);
    ((u16x8*)xb)[t] = o;
  } else if(bid < 9216){
    int j = bid - 8192;
    transpose_body<1>(Whg, wt, (j&63)*64, (j>>6)*64, 1024, 4096, tile, tid);
  } else {
    int j = bid - 9216;
    transpose_body<0>(Wout, wo, (j&15)*64, (j>>4)*64, 2048, 1024, tile, tid);
  }
}

// ---- bf16 MFMA GEMM, A(M,K) row-major, Bt(N,K) row-major, 128x128 tile, BK=64.
// LDS row stride = 64 shorts (128 B); rank-8 XOR swizzle: LDS slot s of row r
// holds global 8-short chunk s ^ (r&7) -> quarter-wave b128 reads hit all 32
// banks 2-way (free); staging stays one 128B segment per 8 lanes.
// EPI=0: fp32 C0 store.  EPI=1: hidden/gate interleaved cols -> c=sigmoid(-gate),
// v=sigmoid(gate)*g(hidden), pair-packed dword stores (shfl_xor lane pairing),
// plus fused 32-row chunk affine summaries -> Ap/Vp (bf16).
template<int EPI>
__global__ __launch_bounds__(256, 2)
void k_gemm(const unsigned short* __restrict__ A, const unsigned short* __restrict__ Bt,
            float* __restrict__ C0, unsigned* __restrict__ U0,
            unsigned* __restrict__ U1, unsigned short* __restrict__ Ap,
            unsigned short* __restrict__ Vp, int M, int N, int K){
  __shared__ unsigned short lsA[128*64];   // 16 KB
  __shared__ unsigned short lsB[128*64];   // 16 KB
  int tid  = threadIdx.x;
  int lane = tid & 63, wave = tid >> 6;
  int wm = wave >> 1, wn = wave & 1;
  int cl = lane & 15, quad = lane >> 4;
  int m0 = blockIdx.y * 128, n0 = blockIdx.x * 128;

  f32x4 acc[4][4];
  #pragma unroll
  for(int i=0;i<4;i++)
    #pragma unroll
    for(int j=0;j<4;j++) acc[i][j] = (f32x4){0.f,0.f,0.f,0.f};

  // staging: thread -> rows (tid>>3)+32*it, LDS slot tid&7,
  // global chunk fetched = (tid&7) ^ ((tid>>3)&7)
  int g = (tid&7) ^ ((tid>>3)&7);
  const unsigned short* gA = A  + (size_t)(m0 + (tid>>3))*K + g*8;
  const unsigned short* gB = Bt + (size_t)(n0 + (tid>>3))*K + g*8;
  unsigned short* dA = lsA + tid*8;
  unsigned short* dB = lsB + tid*8;

  for(int k0=0; k0<K; k0+=64){
    #pragma unroll
    for(int it=0; it<4; it++){
      async16(dA + it*2048, gA + (size_t)(it*32)*K + k0);
      async16(dB + it*2048, gB + (size_t)(it*32)*K + k0);
    }
    __syncthreads();
    #pragma unroll
    for(int kh=0; kh<2; kh++){
      bf16x8 fa[4], fb[4];
      int sl = ((kh<<2)|quad);
      #pragma unroll
      for(int t2=0;t2<4;t2++){
        int ra = wm*64 + t2*16 + cl;
        int rb = wn*64 + t2*16 + cl;
        fa[t2] = *(const bf16x8*)&lsA[ra*64 + (sl^(cl&7))*8];
        fb[t2] = *(const bf16x8*)&lsB[rb*64 + (sl^(cl&7))*8];
      }
      #pragma unroll
      for(int i=0;i<4;i++)
        #pragma unroll
        for(int j=0;j<4;j++)
          acc[i][j] = __builtin_amdgcn_mfma_f32_16x16x32_bf16(fa[i], fb[j], acc[i][j], 0, 0, 0);
    }
    __syncthreads();
  }

  if(EPI==0){
    #pragma unroll
    for(int i=0;i<4;i++)
      #pragma unroll
      for(int j=0;j<4;j++){
        int n = n0 + wn*64 + j*16 + cl;
        #pragma unroll
        for(int r=0;r<4;r++){
          int m = m0 + wm*64 + i*16 + quad*4 + r;
          C0[(size_t)m*N + n] = acc[i][j][r];
        }
      }
  } else {
    // Fused scan summary: per-lane 4-row partial maps -> seg-major LDS
    // (32 segs of 4 rows), then 256 threads compose 8 segs each into
    // four 32-row chunk summaries (bf16).
    float* lA_f = (float*)lsA;   // [seg(32)][ch(64)] = 8 KB
    float* lV_f = (float*)lsB;
    int ibase = ((n0 + wn*64) >> 1) + cl;
    int odd = cl & 1;
    #pragma unroll
    for(int i=0;i<4;i++)
      #pragma unroll
      for(int p=0;p<2;p++){
        f32x4 hh = acc[i][2*p], gg = acc[i][2*p+1];
        int ii = ibase + p*16;
        float pa = 1.f, pv = 0.f;
        #pragma unroll
        for(int r=0;r<4;r++){
          int m = m0 + wm*64 + i*16 + quad*4 + r;   // flat (b*T+t)
          float gate = gg[r], hid = hh[r];
          float e  = __expf(gate);
          float cc = 1.f/(1.f + e);                 // sigmoid(-gate)
          float z  = (gate > 80.f) ? 1.f : e*cc;    // sigmoid(gate)
          float gv = (hid >= 0.f) ? (hid + 0.5f) : (1.f/(1.f + __expf(-hid)));
          float vv = z*gv;
          // pair-pack: lane cl^1 holds the adjacent channel of the same row
          float ccp = __shfl_xor(cc, 1, 64);
          float vvp = __shfl_xor(vv, 1, 64);
          unsigned wlo = odd ? (unsigned)f2bf(vvp) : (unsigned)f2bf(cc);
          unsigned whi = odd ? (unsigned)f2bf(vv)  : (unsigned)f2bf(ccp);
          unsigned* dst = odd ? U1 : U0;
          dst[((size_t)m*DI + (ii & ~1)) >> 1] = wlo | (whi << 16);
          pa *= cc;
          pv = fmaf(cc, pv, vv);
        }
        int seg = wm*16 + i*4 + quad;
        int chl = wn*32 + p*16 + cl;
        lA_f[seg*64 + chl] = pa;
        lV_f[seg*64 + chl] = pv;
      }
    __syncthreads();
    {
      int ch = tid & 63, q = tid >> 6;              // q = 32-row chunk in block
      float Ac = 1.f, Vc = 0.f;
      #pragma unroll
      for(int s=0; s<8; s++){
        int idx = (q*8 + s)*64 + ch;
        float a = lA_f[idx], v = lV_f[idx];
        Ac *= a;
        Vc = fmaf(a, Vc, v);
      }
      int b = m0 >> 12;
      int ch32 = ((m0 & 4095) >> 5) + q;            // 32-row chunk index in batch
      size_t o = (size_t)(b*NC2 + ch32)*DI + (n0 >> 1) + ch;
      Ap[o] = f2bf(Ac); Vp[o] = f2bf(Vc);
    }
  }
}

// ---- scan phase B: sequential combine over 128 chunks (bf16 summaries);
//      hin (bf16) written in-place over Ap ----
__global__ __launch_bounds__(256) void k_scanB(const float* __restrict__ prev,
                                               unsigned short* __restrict__ Ap,
                                               const unsigned short* __restrict__ Vp){
  int t = blockIdx.x*256 + threadIdx.x;     // 8192 = B*DI
  int i = t & (DI-1); int b = t >> 11;
  float h = fmaxf(prev[t], 1e-8f);          // h_0
  for(int ch=0; ch<NC2; ch++){
    size_t o = (size_t)(b*NC2 + ch)*DI + i;
    float a = bf2f_s(Ap[o]), vv = bf2f_s(Vp[o]);
    Ap[o] = f2bf(h);                         // hin for this chunk
    h = fmaf(a, h, vv);
  }
}

// ---- scan phase C: recurrence per 32-chunk; h (bf16) overwrites v in place;
//      next_hidden (fp32) from last chunk ----
__global__ __launch_bounds__(256) void k_scanC(const unsigned* __restrict__ cp,
                                               unsigned* __restrict__ vp,
                                               const unsigned* __restrict__ hinp,
                                               float* __restrict__ nh){
  int t = blockIdx.x*256 + threadIdx.x;     // 524288 = B*NC2*DI/2
  int i2 = t & (DI/2 - 1);
  int ch = (t >> 10) & (NC2-1);
  int b  = t >> 17;
  size_t base = ((size_t)(b*T_LEN + ch*CHL2))*(DI/2) + i2;
  unsigned hp = hinp[(size_t)(b*NC2 + ch)*(DI/2) + i2];
  float h0 = bf2f_lo(hp), h1 = bf2f_hi(hp);
  #pragma unroll 4
  for(int s=0; s<CHL2; s++){
    unsigned cu = cp[base], vu = vp[base];
    h0 = fmaf(bf2f_lo(cu), h0, bf2f_lo(vu));
    h1 = fmaf(bf2f_hi(cu), h1, bf2f_hi(vu));
    vp[base] = (unsigned)f2bf(h0) | ((unsigned)f2bf(h1) << 16);
    base += DI/2;
  }
  if(ch == NC2-1){ nh[b*DI + 2*i2] = h0; nh[b*DI + 2*i2 + 1] = h1; }
}

extern "C" void kernel_launch(void* const* d_in, const int* in_sizes, int n_in,
                              void* d_out, int out_size, void* d_ws, size_t ws_size,
                              hipStream_t stream){
  const float* x    = (const float*)d_in[0];   // (4,4096,1024)
  const float* prev = (const float*)d_in[1];   // (4,2048)
  const float* Whg  = (const float*)d_in[2];   // (1024,4096)
  const float* Wout = (const float*)d_in[3];   // (2048,1024)
  float* out = (float*)d_out;                  // (4,4096,1024) fp32
  float* nh  = out + (size_t)MM*D_IN;          // (4,2048) fp32

  // workspace layout (total 117,440,512 B — proven available in R4)
  const size_t NEED = 117440512;
  if(ws_size < NEED){
    fprintf(stderr, "kernel_launch: ws_size=%zu < needed %zu — aborting launch\n",
            ws_size, NEED);
    return;
  }
  char* ws = (char*)d_ws;
  unsigned short* xb = (unsigned short*)(ws);                    // 33,554,432 B bf16 x
  unsigned short* wt = (unsigned short*)(ws + 33554432);         //  8,388,608 B (4096x1024)
  unsigned short* wo = (unsigned short*)(ws + 41943040);         //  4,194,304 B (1024x2048)
  unsigned short* v  = (unsigned short*)(ws + 46137344);         // 67,108,864 B bf16 v (h in-place)
  unsigned short* Ap = (unsigned short*)(ws + 113246208);        // 2,097,152 B bf16 (hin in-place)
  unsigned short* Vp = (unsigned short*)(ws + 115343360);        // 2,097,152 B bf16
  // c (bf16, 33.5M elems = 64 MB) parked in d_out's `out` region (dead until GEMM2)
  unsigned* c = (unsigned*)d_out;

  k_prep<<<9728, 256, 0, stream>>>(x, xb, Whg, wt, Wout, wo);

  // GEMM1: (16384x1024)x(1024x4096) -> c (d_out), v (ws), fused scanA -> Ap/Vp
  k_gemm<1><<<dim3(32,128), 256, 0, stream>>>(xb, wt, nullptr, c, (unsigned*)v,
                                              Ap, Vp, MM, 2*DI, D_IN);

  k_scanB<<<32,   256, 0, stream>>>(prev, Ap, Vp);
  k_scanC<<<2048, 256, 0, stream>>>((const unsigned*)c, (unsigned*)v,
                                    (const unsigned*)Ap, nh);

  // GEMM2: (16384x2048)x(2048x1024) -> out  (overwrites the c region last)
  k_gemm<0><<<dim3(8,128), 256, 0, stream>>>(v, wo, out, nullptr, nullptr,
                                             nullptr, nullptr, MM, D_IN, DI);
}